// Round 15
// baseline (8745.972 us; speedup 1.0000x reference)
//
#include <hip/hip_runtime.h>
#include <hip/hip_bf16.h>
#include <math.h>

// Problem dims: B=256, K(beams)=128, H=512, D=64, DEPTH=16
#define NB    256
#define NK    128
#define NH    512
#define ND    64
#define NDEPTH 16
#define BKROWS (NB*NK)          // 32768
#define TEMPD 20.0

typedef double d4 __attribute__((ext_vector_type(4)));

// ---------------- init
__global__ void k_init(const float* __restrict__ root, float* __restrict__ states,
                       double* __restrict__ scores, unsigned char* __restrict__ hist) {
    int idx = blockIdx.x * 256 + threadIdx.x;          // 0 .. 16,777,215
    states[idx] = root[idx & (NH - 1)];
    if (idx < BKROWS) scores[idx] = ((idx & (NK - 1)) == 0) ? 0.0 : -1e9;
    if (idx < BKROWS * NDEPTH) hist[idx] = 0;
}

// ---------------- K1+K2 fused: logits GEMM (f64 MFMA) + log-softmax + top-128 + hist gather.
// grid 256 (one block per batch), 512 threads = 8 waves. (round-14 form, kept)
__global__ void __launch_bounds__(512)
k_ltk(const float* __restrict__ states,
      const float* __restrict__ Wl,      // [H][D] f32 row-major
      const float* __restrict__ bl,      // [D]
      double* __restrict__ scores,       // [B*K] read (old) then written (new)
      int* __restrict__ parent, int* __restrict__ decs,
      const unsigned char* __restrict__ hist_in,
      unsigned char* __restrict__ hist_out,
      int tstep)
{
    extern __shared__ char smem[];
    double* L   = (double*)smem;                 // [128][65] (epilogue/topk phase)
    double* wl  = (double*)smem;                 // [16][64]  GEMM phase (aliases L)
    double* stT = (double*)(smem + 8192);        // [16][131] GEMM phase (aliases L)
    int* sp = (int*)(smem + 66560);              // [128]
    int* sd = sp + NK;                           // [128]
    // dynamic LDS = 67584 B (proven size)

    const int b    = blockIdx.x;
    const int rowb = b * NK;
    const int t    = threadIdx.x;
    const int lane = t & 63;
    const int wv   = t >> 6;                     // 0..7
    const int li   = lane & 15;
    const int kq   = lane >> 4;

    const int wrow = t >> 5, wcp = t & 31;       // W staging: 1 double2/thread
    const int sr = t >> 3, scp = t & 7;          // S staging: rows j*64+sr

    d4 acc[4];
    #pragma unroll
    for (int c = 0; c < 4; ++c) { acc[c][0]=0.0; acc[c][1]=0.0; acc[c][2]=0.0; acc[c][3]=0.0; }

    for (int kc = 0; kc < NH; kc += 16) {
        {
            float2 v = *(const float2*)&Wl[(size_t)(kc + wrow) * ND + 2 * wcp];
            double2 d; d.x = (double)v.x; d.y = (double)v.y;
            *(double2*)&wl[wrow * 64 + 2 * wcp] = d;
        }
        #pragma unroll
        for (int j = 0; j < 2; ++j) {
            int r = j * 64 + sr;
            float2 v = *(const float2*)&states[(size_t)(rowb + r) * NH + kc + 2 * scp];
            stT[(2 * scp) * 131 + r]     = (double)v.x;
            stT[(2 * scp + 1) * 131 + r] = (double)v.y;
        }
        __syncthreads();

        #pragma unroll
        for (int ks = 0; ks < 4; ++ks) {
            int kk = 4 * ks + kq;
            double a  = stT[kk * 131 + wv * 16 + li];
            double b0 = wl[kk * 64 +      li];
            double b1 = wl[kk * 64 + 16 + li];
            double b2 = wl[kk * 64 + 32 + li];
            double b3 = wl[kk * 64 + 48 + li];
            acc[0] = __builtin_amdgcn_mfma_f64_16x16x4f64(a, b0, acc[0], 0, 0, 0);
            acc[1] = __builtin_amdgcn_mfma_f64_16x16x4f64(a, b1, acc[1], 0, 0, 0);
            acc[2] = __builtin_amdgcn_mfma_f64_16x16x4f64(a, b2, acc[2], 0, 0, 0);
            acc[3] = __builtin_amdgcn_mfma_f64_16x16x4f64(a, b3, acc[3], 0, 0, 0);
        }
        __syncthreads();   // after last chunk: GEMM LDS reads done -> L may overwrite
    }

    const double bd0 = (double)bl[li];
    const double bd1 = (double)bl[16 + li];
    const double bd2 = (double)bl[32 + li];
    const double bd3 = (double)bl[48 + li];
    #pragma unroll
    for (int n = 0; n < 4; ++n) {
        int rl = wv * 16 + kq + 4 * n;               // local row 0..127
        double x0 = (acc[0][n] + bd0) / TEMPD;
        double x1 = (acc[1][n] + bd1) / TEMPD;
        double x2 = (acc[2][n] + bd2) / TEMPD;
        double x3 = (acc[3][n] + bd3) / TEMPD;
        double m = fmax(fmax(x0, x1), fmax(x2, x3));
        #pragma unroll
        for (int off = 1; off <= 8; off <<= 1) m = fmax(m, __shfl_xor(m, off, 64));
        double e = exp(x0 - m) + exp(x1 - m) + exp(x2 - m) + exp(x3 - m);
        #pragma unroll
        for (int off = 1; off <= 8; off <<= 1) e += __shfl_xor(e, off, 64);
        double ls = log(e);
        double sc = scores[rowb + rl];
        L[rl * 65 +      li] = sc + x0 - m - ls;
        L[rl * 65 + 16 + li] = sc + x1 - m - ls;
        L[rl * 65 + 32 + li] = sc + x2 - m - ls;
        L[rl * 65 + 48 + li] = sc + x3 - m - ls;
    }
    __syncthreads();

    // top-128 selection (value desc, index asc): single wave, zero barriers in loop
    if (t < 64) {
        const int ln = t;
        double mv = L[ln]; int mi = ln;
        for (int i = 1; i < 128; ++i) {
            double v = L[i * 65 + ln];
            if (v > mv) { mv = v; mi = i * 64 + ln; }
        }
        for (int it = 0; it < NK; ++it) {
            double m = mv; int idx = mi;
            #pragma unroll
            for (int off = 1; off <= 32; off <<= 1) {
                double m2 = __shfl_xor(m, off, 64);
                int    i2 = __shfl_xor(idx, off, 64);
                if (m2 > m || (m2 == m && i2 < idx)) { m = m2; idx = i2; }
            }
            const int wrw = idx >> 6, wcol = idx & 63;
            if (ln == 0) {
                scores[b * NK + it] = m;
                parent[b * NK + it] = wrw;
                decs  [b * NK + it] = wcol;
                sp[it] = wrw; sd[it] = wcol;
            }
            if (ln == wcol) L[wrw * 65 + wcol] = -INFINITY;
            double r0 = L[(2 * ln) * 65 + wcol];
            double r1 = L[(2 * ln + 1) * 65 + wcol];
            double rm; int ri;
            if (r1 > r0) { rm = r1; ri = (2 * ln + 1) * 64 + wcol; }
            else         { rm = r0; ri = (2 * ln) * 64 + wcol; }
            #pragma unroll
            for (int off = 1; off <= 32; off <<= 1) {
                double m2 = __shfl_xor(rm, off, 64);
                int    i2 = __shfl_xor(ri, off, 64);
                if (m2 > rm || (m2 == rm && i2 < ri)) { rm = m2; ri = i2; }
            }
            if (ln == wcol) { mv = rm; mi = ri; }
        }
    }
    __syncthreads();

    for (int i = t; i < NK * NDEPTH; i += 512) {
        int k = i >> 4, j = i & 15;
        hist_out[(b * NK + k) * NDEPTH + j] = (j == tstep) ? (unsigned char)sd[k]
                                            : hist_in[(b * NK + sp[k]) * NDEPTH + j];
    }
}

// ---------------- K3: f64 MFMA RNN step, RETILED for cross-block overlap.
// grid (512, 8), 128 threads = 2 waves. Block 64 rows x 64 cols; wave wm: rows wm*32..+31.
// LDS 17.3 KB -> ~9 resident blocks/CU = 4-5 independent barrier domains per SIMD
// (the proven m114 mechanism). Wave tile = round-9 shape (32x64, acc[2][4]);
// per-element FMA order bitwise identical to round 9.
// wt[16][64]: B-reads stride-1; stT[16][67]: A-reads stride-1 (measured conflict-free).
__global__ void __launch_bounds__(128, 4)
k_rnn(const float* __restrict__ states_in,
      const float* __restrict__ Whh,   // [H][H] f32 row-major
      const float* __restrict__ bhh,
      const float* __restrict__ emb,   // [D][H]
      const int* __restrict__ parent, const int* __restrict__ decs,
      float* __restrict__ states_out)
{
    __shared__ double wt[16][64];    // [kk][col] 8192 B
    __shared__ double stT[16][67];   // [kk][r]   8576 B
    __shared__ int sp[64], sd[64];

    const int rowb = blockIdx.x * 64;
    const int colb = blockIdx.y * 64;
    const int t    = threadIdx.x;    // 0..127
    const int lane = t & 63;
    const int li   = lane & 15;
    const int kq   = lane >> 4;      // 0..3
    const int wm   = t >> 6;         // wave 0,1 -> row half

    if (t < 64) { sp[t] = parent[rowb + t]; sd[t] = decs[rowb + t]; }
    __syncthreads();

    int srow[4];
    #pragma unroll
    for (int j = 0; j < 4; ++j) {
        int r = j * 16 + (t >> 3);
        srow[j] = ((rowb + r) >> 7) * NK + sp[r];
    }
    const int scp = t & 7;

    d4 acc[2][4];
    #pragma unroll
    for (int i = 0; i < 2; ++i)
        #pragma unroll
        for (int j = 0; j < 4; ++j) { acc[i][j][0]=0.0; acc[i][j][1]=0.0; acc[i][j][2]=0.0; acc[i][j][3]=0.0; }

    for (int kc = 0; kc < NH; kc += 16) {
        // W tile: 512 double2 from f32 Whh, linear b128 writes, 4/thread
        #pragma unroll
        for (int j = 0; j < 4; ++j) {
            int idx = j * 128 + t;
            int row = idx >> 5, cp = idx & 31;
            float2 v = *(const float2*)&Whh[(size_t)(kc + row) * NH + colb + 2 * cp];
            double2 d; d.x = (double)v.x; d.y = (double)v.y;
            *(double2*)&wt[row][2 * cp] = d;
        }
        // S tile (gathered, transposed): stT[kk][r] = S[parent[r]][kc+kk], 4/thread
        #pragma unroll
        for (int j = 0; j < 4; ++j) {
            int r = j * 16 + (t >> 3);
            float2 v = *(const float2*)&states_in[(size_t)srow[j] * NH + kc + 2 * scp];
            stT[2 * scp][r]     = (double)v.x;
            stT[2 * scp + 1][r] = (double)v.y;
        }
        __syncthreads();

        #pragma unroll
        for (int ks = 0; ks < 4; ++ks) {
            int kk = 4 * ks + kq;
            double a0 = stT[kk][wm * 32 + li];
            double a1 = stT[kk][wm * 32 + 16 + li];
            double b0 = wt[kk][     li];
            double b1 = wt[kk][16 + li];
            double b2 = wt[kk][32 + li];
            double b3 = wt[kk][48 + li];
            acc[0][0] = __builtin_amdgcn_mfma_f64_16x16x4f64(a0, b0, acc[0][0], 0, 0, 0);
            acc[0][1] = __builtin_amdgcn_mfma_f64_16x16x4f64(a0, b1, acc[0][1], 0, 0, 0);
            acc[0][2] = __builtin_amdgcn_mfma_f64_16x16x4f64(a0, b2, acc[0][2], 0, 0, 0);
            acc[0][3] = __builtin_amdgcn_mfma_f64_16x16x4f64(a0, b3, acc[0][3], 0, 0, 0);
            acc[1][0] = __builtin_amdgcn_mfma_f64_16x16x4f64(a1, b0, acc[1][0], 0, 0, 0);
            acc[1][1] = __builtin_amdgcn_mfma_f64_16x16x4f64(a1, b1, acc[1][1], 0, 0, 0);
            acc[1][2] = __builtin_amdgcn_mfma_f64_16x16x4f64(a1, b2, acc[1][2], 0, 0, 0);
            acc[1][3] = __builtin_amdgcn_mfma_f64_16x16x4f64(a1, b3, acc[1][3], 0, 0, 0);
        }
        __syncthreads();
    }

    // epilogue: D[i][j]: j = lane&15, i = (lane>>4) + 4n (verified L1)
    #pragma unroll
    for (int ct = 0; ct < 4; ++ct) {
        int col = colb + ct * 16 + li;
        double bb = (double)bhh[col];
        #pragma unroll
        for (int rt = 0; rt < 2; ++rt) {
            #pragma unroll
            for (int n = 0; n < 4; ++n) {
                int rL = wm * 32 + rt * 16 + kq + 4 * n;
                double e = (double)emb[(size_t)sd[rL] * NH + col];
                double z = acc[rt][ct][n] + bb + e;
                states_out[(size_t)(rowb + rL) * NH + col] = (float)tanh(z);
            }
        }
    }
}

// ---------------- finalize: d_out = [hist as float (524288), scores as float (32768)]
__global__ void k_final(const unsigned char* __restrict__ hist,
                        const double* __restrict__ scores,
                        float* __restrict__ out)
{
    int i = blockIdx.x * 256 + threadIdx.x;
    const int nh = BKROWS * NDEPTH;      // 524288
    if (i < nh) out[i] = (float)hist[i];
    else if (i < nh + BKROWS) out[i] = (float)scores[i - nh];
}

extern "C" void kernel_launch(void* const* d_in, const int* in_sizes, int n_in,
                              void* d_out, int out_size, void* d_ws, size_t ws_size,
                              hipStream_t stream) {
    // inputs: env(unused), root_state, W_logits, b_logits, W_hh, b_hh, emb, beams(=128)
    const float* root = (const float*)d_in[1];
    const float* Wl   = (const float*)d_in[2];
    const float* bl   = (const float*)d_in[3];
    const float* Whh  = (const float*)d_in[4];
    const float* bhh  = (const float*)d_in[5];
    const float* emb  = (const float*)d_in[6];

    char* ws = (char*)d_ws;
    double* scores       = (double*)(ws + 0);             //    262,144
    float*  sA           = (float*)(ws + 262144);         // 67,108,864
    float*  sB           = (float*)(ws + 67371008);       // 67,108,864
    int*    parent       = (int*)(ws + 134479872);        //    131,072
    int*    decs         = (int*)(ws + 134610944);        //    131,072
    unsigned char* hA    = (unsigned char*)(ws + 134742016); // 524,288
    unsigned char* hB    = (unsigned char*)(ws + 135266304); // 524,288
    // total 135,790,592 bytes (<= proven 155,713,536)

    k_init<<<65536, 256, 0, stream>>>(root, sA, scores, hA);

    float* scur = sA; float* snxt = sB;
    unsigned char* hcur = hA; unsigned char* hnxt = hB;
    for (int t = 0; t < NDEPTH; ++t) {
        k_ltk<<<256, 512, 67584, stream>>>(scur, Wl, bl, scores, parent, decs, hcur, hnxt, t);
        k_rnn<<<dim3(512, 8), 128, 0, stream>>>(scur, Whh, bhh, emb, parent, decs, snxt);
        { float* tmp = scur; scur = snxt; snxt = tmp; }
        { unsigned char* tmp = hcur; hcur = hnxt; hnxt = tmp; }
    }

    k_final<<<2176, 256, 0, stream>>>(hcur, scores, (float*)d_out);
}

// Round 16
// 8682.029 us; speedup vs baseline: 1.0074x; 1.0074x over previous
//
#include <hip/hip_runtime.h>
#include <hip/hip_bf16.h>
#include <math.h>

// Problem dims: B=256, K(beams)=128, H=512, D=64, DEPTH=16
#define NB    256
#define NK    128
#define NH    512
#define ND    64
#define NDEPTH 16
#define BKROWS (NB*NK)          // 32768
#define TEMPD 20.0

typedef double d4 __attribute__((ext_vector_type(4)));

// ---------------- init
__global__ void k_init(const float* __restrict__ root, float* __restrict__ states,
                       double* __restrict__ scores, unsigned char* __restrict__ hist) {
    int idx = blockIdx.x * 256 + threadIdx.x;          // 0 .. 16,777,215
    states[idx] = root[idx & (NH - 1)];
    if (idx < BKROWS) scores[idx] = ((idx & (NK - 1)) == 0) ? 0.0 : -1e9;
    if (idx < BKROWS * NDEPTH) hist[idx] = 0;
}

// ---------------- K1+K2 fused: logits GEMM (f64 MFMA) + log-softmax + top-128 + hist gather.
// grid 256 (one block per batch), 512 threads = 8 waves. Block: 128 rows x 64 cols.
// K-chunk 32 (16 barriers instead of 32; per-lane MFMA k-order identical to chunk-16).
// GEMM tiles wl/stT ALIAS the topk buffer L (GEMM usage 49.9 KB < 66.5 KB L region).
// Layouts (probe-verified): A[i][k] i=lane&15,k=lane>>4; B[k][j] j=lane&15,k=lane>>4;
// D[i][j]: j=lane&15, i=(lane>>4)+4*n.
__global__ void __launch_bounds__(512)
k_ltk(const float* __restrict__ states,
      const float* __restrict__ Wl,      // [H][D] f32 row-major
      const float* __restrict__ bl,      // [D]
      double* __restrict__ scores,       // [B*K] read (old) then written (new)
      int* __restrict__ parent, int* __restrict__ decs,
      const unsigned char* __restrict__ hist_in,
      unsigned char* __restrict__ hist_out,
      int tstep)
{
    extern __shared__ char smem[];
    double* L   = (double*)smem;                 // [128][65] (epilogue/topk phase)
    double* wl  = (double*)smem;                 // [32][64]  GEMM phase (aliases L, 16384 B)
    double* stT = (double*)(smem + 16384);       // [32][131] GEMM phase (aliases L, 33536 B)
    int* sp = (int*)(smem + 66560);              // [128]
    int* sd = sp + NK;                           // [128]
    // dynamic LDS = 67584 B (proven size)

    const int b    = blockIdx.x;
    const int rowb = b * NK;
    const int t    = threadIdx.x;
    const int lane = t & 63;
    const int wv   = t >> 6;                     // 0..7
    const int li   = lane & 15;
    const int kq   = lane >> 4;

    d4 acc[4];
    #pragma unroll
    for (int c = 0; c < 4; ++c) { acc[c][0]=0.0; acc[c][1]=0.0; acc[c][2]=0.0; acc[c][3]=0.0; }

    for (int kc = 0; kc < NH; kc += 32) {
        // W tile: rows kc..kc+31 x 64 cols = 1024 double2, 2/thread, linear b128 writes
        #pragma unroll
        for (int j = 0; j < 2; ++j) {
            int idx = j * 512 + t;
            int row = idx >> 5, cp = idx & 31;
            float2 v = *(const float2*)&Wl[(size_t)(kc + row) * ND + 2 * cp];
            double2 d; d.x = (double)v.x; d.y = (double)v.y;
            *(double2*)&wl[row * 64 + 2 * cp] = d;
        }
        // S tile transposed: stT[kk][r] = S[rowb+r][kc+kk], kk=0..31, r=0..127; 4/thread
        #pragma unroll
        for (int j = 0; j < 4; ++j) {
            int idx = j * 512 + t;
            int r = idx >> 4, cp = idx & 15;
            float2 v = *(const float2*)&states[(size_t)(rowb + r) * NH + kc + 2 * cp];
            stT[(2 * cp) * 131 + r]     = (double)v.x;
            stT[(2 * cp + 1) * 131 + r] = (double)v.y;
        }
        __syncthreads();

        #pragma unroll
        for (int ks = 0; ks < 8; ++ks) {
            int kk = 4 * ks + kq;                // same ascending per-lane k-order
            double a  = stT[kk * 131 + wv * 16 + li];
            double b0 = wl[kk * 64 +      li];
            double b1 = wl[kk * 64 + 16 + li];
            double b2 = wl[kk * 64 + 32 + li];
            double b3 = wl[kk * 64 + 48 + li];
            acc[0] = __builtin_amdgcn_mfma_f64_16x16x4f64(a, b0, acc[0], 0, 0, 0);
            acc[1] = __builtin_amdgcn_mfma_f64_16x16x4f64(a, b1, acc[1], 0, 0, 0);
            acc[2] = __builtin_amdgcn_mfma_f64_16x16x4f64(a, b2, acc[2], 0, 0, 0);
            acc[3] = __builtin_amdgcn_mfma_f64_16x16x4f64(a, b3, acc[3], 0, 0, 0);
        }
        __syncthreads();   // after last chunk: GEMM LDS reads done -> L may overwrite
    }

    // epilogue: logp + old score -> L[row][col] (the topk staging layout)
    const double bd0 = (double)bl[li];
    const double bd1 = (double)bl[16 + li];
    const double bd2 = (double)bl[32 + li];
    const double bd3 = (double)bl[48 + li];
    #pragma unroll
    for (int n = 0; n < 4; ++n) {
        int rl = wv * 16 + kq + 4 * n;               // local row 0..127
        double x0 = (acc[0][n] + bd0) / TEMPD;
        double x1 = (acc[1][n] + bd1) / TEMPD;
        double x2 = (acc[2][n] + bd2) / TEMPD;
        double x3 = (acc[3][n] + bd3) / TEMPD;
        double m = fmax(fmax(x0, x1), fmax(x2, x3));
        #pragma unroll
        for (int off = 1; off <= 8; off <<= 1) m = fmax(m, __shfl_xor(m, off, 64));
        double e = exp(x0 - m) + exp(x1 - m) + exp(x2 - m) + exp(x3 - m);
        #pragma unroll
        for (int off = 1; off <= 8; off <<= 1) e += __shfl_xor(e, off, 64);
        double ls = log(e);
        double sc = scores[rowb + rl];
        L[rl * 65 +      li] = sc + x0 - m - ls;
        L[rl * 65 + 16 + li] = sc + x1 - m - ls;
        L[rl * 65 + 32 + li] = sc + x2 - m - ls;
        L[rl * 65 + 48 + li] = sc + x3 - m - ls;
    }
    __syncthreads();

    // top-128 selection (value desc, index asc): single wave, zero barriers in loop
    if (t < 64) {
        const int ln = t;
        double mv = L[ln]; int mi = ln;
        for (int i = 1; i < 128; ++i) {
            double v = L[i * 65 + ln];
            if (v > mv) { mv = v; mi = i * 64 + ln; }
        }
        for (int it = 0; it < NK; ++it) {
            double m = mv; int idx = mi;
            #pragma unroll
            for (int off = 1; off <= 32; off <<= 1) {
                double m2 = __shfl_xor(m, off, 64);
                int    i2 = __shfl_xor(idx, off, 64);
                if (m2 > m || (m2 == m && i2 < idx)) { m = m2; idx = i2; }
            }
            const int wrw = idx >> 6, wcol = idx & 63;
            if (ln == 0) {
                scores[b * NK + it] = m;
                parent[b * NK + it] = wrw;
                decs  [b * NK + it] = wcol;
                sp[it] = wrw; sd[it] = wcol;
            }
            if (ln == wcol) L[wrw * 65 + wcol] = -INFINITY;
            double r0 = L[(2 * ln) * 65 + wcol];
            double r1 = L[(2 * ln + 1) * 65 + wcol];
            double rm; int ri;
            if (r1 > r0) { rm = r1; ri = (2 * ln + 1) * 64 + wcol; }
            else         { rm = r0; ri = (2 * ln) * 64 + wcol; }
            #pragma unroll
            for (int off = 1; off <= 32; off <<= 1) {
                double m2 = __shfl_xor(rm, off, 64);
                int    i2 = __shfl_xor(ri, off, 64);
                if (m2 > rm || (m2 == rm && i2 < ri)) { rm = m2; ri = i2; }
            }
            if (ln == wcol) { mv = rm; mi = ri; }
        }
    }
    __syncthreads();

    // hist gather: hist_out[b,k,:] = hist_in[b,sp[k],:]; [:,tstep] = sd[k]
    for (int i = t; i < NK * NDEPTH; i += 512) {
        int k = i >> 4, j = i & 15;
        hist_out[(b * NK + k) * NDEPTH + j] = (j == tstep) ? (unsigned char)sd[k]
                                            : hist_in[(b * NK + sp[k]) * NDEPTH + j];
    }
}

// ---------------- K3: f64 MFMA RNN step (round-9 form -- measured best: 366 us, MfmaUtil 65%,
// reproduced three times; all structural variants regressed).
// grid (512, 4), 256 threads = 4 waves. Block 64 rows x 128 cols; wave (wm,wn): 32x64.
// wt[16][128]: B-reads stride-1; stT[16][67]: A-reads stride-1 (measured conflict-free).
__global__ void __launch_bounds__(256, 4)
k_rnn(const float* __restrict__ states_in,
      const float* __restrict__ Whh,   // [H][H] f32 row-major
      const float* __restrict__ bhh,
      const float* __restrict__ emb,   // [D][H]
      const int* __restrict__ parent, const int* __restrict__ decs,
      float* __restrict__ states_out)
{
    __shared__ double wt[16][128];   // [kk][col]
    __shared__ double stT[16][67];   // [kk][r]
    __shared__ int sp[64], sd[64];

    const int rowb = blockIdx.x * 64;
    const int cbk  = blockIdx.y;
    const int colb = cbk * 128;
    const int t    = threadIdx.x;
    const int lane = t & 63;
    const int li   = lane & 15;
    const int kq   = lane >> 4;     // 0..3
    const int wv   = t >> 6;
    const int wm   = wv >> 1;       // row-group (0,1)
    const int wn   = wv & 1;        // col-group (0,1)

    if (t < 64) { sp[t] = parent[rowb + t]; sd[t] = decs[rowb + t]; }
    __syncthreads();

    int srow[2];
    #pragma unroll
    for (int j = 0; j < 2; ++j) {
        int r = (j * 256 + t) >> 3;
        srow[j] = ((rowb + r) >> 7) * NK + sp[r];
    }

    d4 acc[2][4];
    #pragma unroll
    for (int i = 0; i < 2; ++i)
        #pragma unroll
        for (int j = 0; j < 4; ++j) { acc[i][j][0]=0.0; acc[i][j][1]=0.0; acc[i][j][2]=0.0; acc[i][j][3]=0.0; }

    for (int kc = 0; kc < NH; kc += 16) {
        // W tile: 1024 double2 from f32 Whh, linear b128 writes
        #pragma unroll
        for (int j = 0; j < 4; ++j) {
            int idx = j * 256 + t;
            int row = idx >> 6, cp = idx & 63;
            float2 v = *(const float2*)&Whh[(size_t)(kc + row) * NH + colb + 2 * cp];
            double2 d; d.x = (double)v.x; d.y = (double)v.y;
            *(double2*)&wt[row][2 * cp] = d;
        }
        // S tile (gathered, transposed): stT[kk][r] = S[parent[r]][kc+kk]
        #pragma unroll
        for (int j = 0; j < 2; ++j) {
            int idx = j * 256 + t;
            int r = idx >> 3, cp = idx & 7;
            float2 v = *(const float2*)&states_in[(size_t)srow[j] * NH + kc + 2 * cp];
            stT[2 * cp][r]     = (double)v.x;
            stT[2 * cp + 1][r] = (double)v.y;
        }
        __syncthreads();

        #pragma unroll
        for (int ks = 0; ks < 4; ++ks) {
            int kk = 4 * ks + kq;
            double a0 = stT[kk][wm * 32 + li];
            double a1 = stT[kk][wm * 32 + 16 + li];
            double b0 = wt[kk][wn * 64 +      li];
            double b1 = wt[kk][wn * 64 + 16 + li];
            double b2 = wt[kk][wn * 64 + 32 + li];
            double b3 = wt[kk][wn * 64 + 48 + li];
            acc[0][0] = __builtin_amdgcn_mfma_f64_16x16x4f64(a0, b0, acc[0][0], 0, 0, 0);
            acc[0][1] = __builtin_amdgcn_mfma_f64_16x16x4f64(a0, b1, acc[0][1], 0, 0, 0);
            acc[0][2] = __builtin_amdgcn_mfma_f64_16x16x4f64(a0, b2, acc[0][2], 0, 0, 0);
            acc[0][3] = __builtin_amdgcn_mfma_f64_16x16x4f64(a0, b3, acc[0][3], 0, 0, 0);
            acc[1][0] = __builtin_amdgcn_mfma_f64_16x16x4f64(a1, b0, acc[1][0], 0, 0, 0);
            acc[1][1] = __builtin_amdgcn_mfma_f64_16x16x4f64(a1, b1, acc[1][1], 0, 0, 0);
            acc[1][2] = __builtin_amdgcn_mfma_f64_16x16x4f64(a1, b2, acc[1][2], 0, 0, 0);
            acc[1][3] = __builtin_amdgcn_mfma_f64_16x16x4f64(a1, b3, acc[1][3], 0, 0, 0);
        }
        __syncthreads();
    }

    // epilogue: D[i][j]: j = lane&15, i = (lane>>4) + 4n (verified L1)
    #pragma unroll
    for (int ct = 0; ct < 4; ++ct) {
        int col = colb + wn * 64 + ct * 16 + li;
        double bb = (double)bhh[col];
        #pragma unroll
        for (int rt = 0; rt < 2; ++rt) {
            #pragma unroll
            for (int n = 0; n < 4; ++n) {
                int rL = wm * 32 + rt * 16 + kq + 4 * n;
                double e = (double)emb[(size_t)sd[rL] * NH + col];
                double z = acc[rt][ct][n] + bb + e;
                states_out[(size_t)(rowb + rL) * NH + col] = (float)tanh(z);
            }
        }
    }
}

// ---------------- finalize: d_out = [hist as float (524288), scores as float (32768)]
__global__ void k_final(const unsigned char* __restrict__ hist,
                        const double* __restrict__ scores,
                        float* __restrict__ out)
{
    int i = blockIdx.x * 256 + threadIdx.x;
    const int nh = BKROWS * NDEPTH;      // 524288
    if (i < nh) out[i] = (float)hist[i];
    else if (i < nh + BKROWS) out[i] = (float)scores[i - nh];
}

extern "C" void kernel_launch(void* const* d_in, const int* in_sizes, int n_in,
                              void* d_out, int out_size, void* d_ws, size_t ws_size,
                              hipStream_t stream) {
    // inputs: env(unused), root_state, W_logits, b_logits, W_hh, b_hh, emb, beams(=128)
    const float* root = (const float*)d_in[1];
    const float* Wl   = (const float*)d_in[2];
    const float* bl   = (const float*)d_in[3];
    const float* Whh  = (const float*)d_in[4];
    const float* bhh  = (const float*)d_in[5];
    const float* emb  = (const float*)d_in[6];

    char* ws = (char*)d_ws;
    double* scores       = (double*)(ws + 0);             //    262,144
    float*  sA           = (float*)(ws + 262144);         // 67,108,864
    float*  sB           = (float*)(ws + 67371008);       // 67,108,864
    int*    parent       = (int*)(ws + 134479872);        //    131,072
    int*    decs         = (int*)(ws + 134610944);        //    131,072
    unsigned char* hA    = (unsigned char*)(ws + 134742016); // 524,288
    unsigned char* hB    = (unsigned char*)(ws + 135266304); // 524,288
    // total 135,790,592 bytes (<= proven 155,713,536)

    k_init<<<65536, 256, 0, stream>>>(root, sA, scores, hA);

    float* scur = sA; float* snxt = sB;
    unsigned char* hcur = hA; unsigned char* hnxt = hB;
    for (int t = 0; t < NDEPTH; ++t) {
        k_ltk<<<256, 512, 67584, stream>>>(scur, Wl, bl, scores, parent, decs, hcur, hnxt, t);
        k_rnn<<<dim3(512, 4), 256, 0, stream>>>(scur, Whh, bhh, emb, parent, decs, snxt);
        { float* tmp = scur; scur = snxt; snxt = tmp; }
        { unsigned char* tmp = hcur; hcur = hnxt; hnxt = tmp; }
    }

    k_final<<<2176, 256, 0, stream>>>(hcur, scores, (float*)d_out);
}

// Round 17
// 8665.462 us; speedup vs baseline: 1.0093x; 1.0019x over previous
//
#include <hip/hip_runtime.h>
#include <hip/hip_bf16.h>
#include <math.h>

// Problem dims: B=256, K(beams)=128, H=512, D=64, DEPTH=16
#define NB    256
#define NK    128
#define NH    512
#define ND    64
#define NDEPTH 16
#define BKROWS (NB*NK)          // 32768
#define TEMPD 20.0

typedef double d4 __attribute__((ext_vector_type(4)));

// ---------------- init
__global__ void k_init(const float* __restrict__ root, float* __restrict__ states,
                       double* __restrict__ scores, unsigned char* __restrict__ hist) {
    int idx = blockIdx.x * 256 + threadIdx.x;          // 0 .. 16,777,215
    states[idx] = root[idx & (NH - 1)];
    if (idx < BKROWS) scores[idx] = ((idx & (NK - 1)) == 0) ? 0.0 : -1e9;
    if (idx < BKROWS * NDEPTH) hist[idx] = 0;
}

// ---------------- K1+K2 fused: logits GEMM (f64 MFMA) + log-softmax + top-128 + hist gather.
// grid 256 (one block per batch), 512 threads = 8 waves. K-chunk 16 (round-14 measured form).
__global__ void __launch_bounds__(512)
k_ltk(const float* __restrict__ states,
      const float* __restrict__ Wl,      // [H][D] f32 row-major
      const float* __restrict__ bl,      // [D]
      double* __restrict__ scores,       // [B*K] read (old) then written (new)
      int* __restrict__ parent, int* __restrict__ decs,
      const unsigned char* __restrict__ hist_in,
      unsigned char* __restrict__ hist_out,
      int tstep)
{
    extern __shared__ char smem[];
    double* L   = (double*)smem;                 // [128][65] (epilogue/topk phase)
    double* wl  = (double*)smem;                 // [16][64]  GEMM phase (aliases L)
    double* stT = (double*)(smem + 8192);        // [16][131] GEMM phase (aliases L)
    int* sp = (int*)(smem + 66560);              // [128]
    int* sd = sp + NK;                           // [128]
    // dynamic LDS = 67584 B (proven size)

    const int b    = blockIdx.x;
    const int rowb = b * NK;
    const int t    = threadIdx.x;
    const int lane = t & 63;
    const int wv   = t >> 6;                     // 0..7
    const int li   = lane & 15;
    const int kq   = lane >> 4;

    const int wrow = t >> 5, wcp = t & 31;       // W staging: 1 double2/thread
    const int sr = t >> 3, scp = t & 7;          // S staging: rows j*64+sr

    d4 acc[4];
    #pragma unroll
    for (int c = 0; c < 4; ++c) { acc[c][0]=0.0; acc[c][1]=0.0; acc[c][2]=0.0; acc[c][3]=0.0; }

    for (int kc = 0; kc < NH; kc += 16) {
        {
            float2 v = *(const float2*)&Wl[(size_t)(kc + wrow) * ND + 2 * wcp];
            double2 d; d.x = (double)v.x; d.y = (double)v.y;
            *(double2*)&wl[wrow * 64 + 2 * wcp] = d;
        }
        #pragma unroll
        for (int j = 0; j < 2; ++j) {
            int r = j * 64 + sr;
            float2 v = *(const float2*)&states[(size_t)(rowb + r) * NH + kc + 2 * scp];
            stT[(2 * scp) * 131 + r]     = (double)v.x;
            stT[(2 * scp + 1) * 131 + r] = (double)v.y;
        }
        __syncthreads();

        #pragma unroll
        for (int ks = 0; ks < 4; ++ks) {
            int kk = 4 * ks + kq;
            double a  = stT[kk * 131 + wv * 16 + li];
            double b0 = wl[kk * 64 +      li];
            double b1 = wl[kk * 64 + 16 + li];
            double b2 = wl[kk * 64 + 32 + li];
            double b3 = wl[kk * 64 + 48 + li];
            acc[0] = __builtin_amdgcn_mfma_f64_16x16x4f64(a, b0, acc[0], 0, 0, 0);
            acc[1] = __builtin_amdgcn_mfma_f64_16x16x4f64(a, b1, acc[1], 0, 0, 0);
            acc[2] = __builtin_amdgcn_mfma_f64_16x16x4f64(a, b2, acc[2], 0, 0, 0);
            acc[3] = __builtin_amdgcn_mfma_f64_16x16x4f64(a, b3, acc[3], 0, 0, 0);
        }
        __syncthreads();   // after last chunk: GEMM LDS reads done -> L may overwrite
    }

    const double bd0 = (double)bl[li];
    const double bd1 = (double)bl[16 + li];
    const double bd2 = (double)bl[32 + li];
    const double bd3 = (double)bl[48 + li];
    #pragma unroll
    for (int n = 0; n < 4; ++n) {
        int rl = wv * 16 + kq + 4 * n;               // local row 0..127
        double x0 = (acc[0][n] + bd0) / TEMPD;
        double x1 = (acc[1][n] + bd1) / TEMPD;
        double x2 = (acc[2][n] + bd2) / TEMPD;
        double x3 = (acc[3][n] + bd3) / TEMPD;
        double m = fmax(fmax(x0, x1), fmax(x2, x3));
        #pragma unroll
        for (int off = 1; off <= 8; off <<= 1) m = fmax(m, __shfl_xor(m, off, 64));
        double e = exp(x0 - m) + exp(x1 - m) + exp(x2 - m) + exp(x3 - m);
        #pragma unroll
        for (int off = 1; off <= 8; off <<= 1) e += __shfl_xor(e, off, 64);
        double ls = log(e);
        double sc = scores[rowb + rl];
        L[rl * 65 +      li] = sc + x0 - m - ls;
        L[rl * 65 + 16 + li] = sc + x1 - m - ls;
        L[rl * 65 + 32 + li] = sc + x2 - m - ls;
        L[rl * 65 + 48 + li] = sc + x3 - m - ls;
    }
    __syncthreads();

    // top-128 selection (value desc, index asc): single wave, zero barriers in loop
    if (t < 64) {
        const int ln = t;
        double mv = L[ln]; int mi = ln;
        for (int i = 1; i < 128; ++i) {
            double v = L[i * 65 + ln];
            if (v > mv) { mv = v; mi = i * 64 + ln; }
        }
        for (int it = 0; it < NK; ++it) {
            double m = mv; int idx = mi;
            #pragma unroll
            for (int off = 1; off <= 32; off <<= 1) {
                double m2 = __shfl_xor(m, off, 64);
                int    i2 = __shfl_xor(idx, off, 64);
                if (m2 > m || (m2 == m && i2 < idx)) { m = m2; idx = i2; }
            }
            const int wrw = idx >> 6, wcol = idx & 63;
            if (ln == 0) {
                scores[b * NK + it] = m;
                parent[b * NK + it] = wrw;
                decs  [b * NK + it] = wcol;
                sp[it] = wrw; sd[it] = wcol;
            }
            if (ln == wcol) L[wrw * 65 + wcol] = -INFINITY;
            double r0 = L[(2 * ln) * 65 + wcol];
            double r1 = L[(2 * ln + 1) * 65 + wcol];
            double rm; int ri;
            if (r1 > r0) { rm = r1; ri = (2 * ln + 1) * 64 + wcol; }
            else         { rm = r0; ri = (2 * ln) * 64 + wcol; }
            #pragma unroll
            for (int off = 1; off <= 32; off <<= 1) {
                double m2 = __shfl_xor(rm, off, 64);
                int    i2 = __shfl_xor(ri, off, 64);
                if (m2 > rm || (m2 == rm && i2 < ri)) { rm = m2; ri = i2; }
            }
            if (ln == wcol) { mv = rm; mi = ri; }
        }
    }
    __syncthreads();

    for (int i = t; i < NK * NDEPTH; i += 512) {
        int k = i >> 4, j = i & 15;
        hist_out[(b * NK + k) * NDEPTH + j] = (j == tstep) ? (unsigned char)sd[k]
                                            : hist_in[(b * NK + sp[k]) * NDEPTH + j];
    }
}

// ---------------- K3: f64 MFMA RNN step, 128x128 tile with 8 waves (round-11 geometry,
// round-9 per-wave shape: 32x64, acc[2][4] -> NO spill, unlike round-11's acc[4][4]).
// grid (256, 4), 512 threads = 8 waves (4 row-groups x 2 col-groups).
// LDS 33.4 KB -> 4 blocks/CU x 512 thr = 2048 thr/CU (full); 1024 blocks = 1 dispatch round.
// Staging ratio 8 double2/MFMA vs round-9's 12. Per-element FMA k-order bitwise identical.
__global__ void __launch_bounds__(512, 2)
k_rnn(const float* __restrict__ states_in,
      const float* __restrict__ Whh,   // [H][H] f32 row-major
      const float* __restrict__ bhh,
      const float* __restrict__ emb,   // [D][H]
      const int* __restrict__ parent, const int* __restrict__ decs,
      float* __restrict__ states_out)
{
    __shared__ double wt[16][128];   // [kk][col] 16384 B -- B-reads stride-1
    __shared__ double stT[16][131];  // [kk][r]   16768 B -- A-reads stride-1
    __shared__ int sp[128], sd[128];

    const int b    = blockIdx.x;          // row-block = one full batch (128 beams)
    const int rowb = b * 128;
    const int colb = blockIdx.y * 128;
    const int t    = threadIdx.x;         // 0..511
    const int lane = t & 63;
    const int li   = lane & 15;
    const int kq   = lane >> 4;     // 0..3
    const int wv   = t >> 6;        // 0..7
    const int wm   = wv >> 1;       // row-group 0..3 (rows wm*32..+31)
    const int wn   = wv & 1;        // col-group 0..1 (cols wn*64..+63)

    if (t < 128) { sp[t] = parent[rowb + t]; sd[t] = decs[rowb + t]; }
    __syncthreads();

    // staging coordinates (constant per thread)
    const int wrow = t >> 6, wcp = t & 63;    // W: rows j*8 + wrow, j=0,1; 2 double2/thread
    const int sr = t >> 3, scp = t & 7;       // S: rows j*64 + sr, j=0,1; 2 double2/thread
    int srow[2];
    srow[0] = b * NK + sp[sr];
    srow[1] = b * NK + sp[64 + sr];

    d4 acc[2][4];
    #pragma unroll
    for (int i = 0; i < 2; ++i)
        #pragma unroll
        for (int j = 0; j < 4; ++j) { acc[i][j][0]=0.0; acc[i][j][1]=0.0; acc[i][j][2]=0.0; acc[i][j][3]=0.0; }

    for (int kc = 0; kc < NH; kc += 16) {
        // W tile: 16 rows x 128 cols = 1024 double2, 2/thread, linear b128 writes
        #pragma unroll
        for (int j = 0; j < 2; ++j) {
            float2 v = *(const float2*)&Whh[(size_t)(kc + j * 8 + wrow) * NH + colb + 2 * wcp];
            double2 d; d.x = (double)v.x; d.y = (double)v.y;
            *(double2*)&wt[j * 8 + wrow][2 * wcp] = d;
        }
        // S tile (gathered, transposed): stT[kk][r] = S[parent[r]][kc+kk], 2/thread
        #pragma unroll
        for (int j = 0; j < 2; ++j) {
            int r = j * 64 + sr;
            float2 v = *(const float2*)&states_in[(size_t)srow[j] * NH + kc + 2 * scp];
            stT[2 * scp][r]     = (double)v.x;
            stT[2 * scp + 1][r] = (double)v.y;
        }
        __syncthreads();

        #pragma unroll
        for (int ks = 0; ks < 4; ++ks) {
            int kk = 4 * ks + kq;
            double a0 = stT[kk][wm * 32 + li];
            double a1 = stT[kk][wm * 32 + 16 + li];
            double b0 = wt[kk][wn * 64 +      li];
            double b1 = wt[kk][wn * 64 + 16 + li];
            double b2 = wt[kk][wn * 64 + 32 + li];
            double b3 = wt[kk][wn * 64 + 48 + li];
            acc[0][0] = __builtin_amdgcn_mfma_f64_16x16x4f64(a0, b0, acc[0][0], 0, 0, 0);
            acc[0][1] = __builtin_amdgcn_mfma_f64_16x16x4f64(a0, b1, acc[0][1], 0, 0, 0);
            acc[0][2] = __builtin_amdgcn_mfma_f64_16x16x4f64(a0, b2, acc[0][2], 0, 0, 0);
            acc[0][3] = __builtin_amdgcn_mfma_f64_16x16x4f64(a0, b3, acc[0][3], 0, 0, 0);
            acc[1][0] = __builtin_amdgcn_mfma_f64_16x16x4f64(a1, b0, acc[1][0], 0, 0, 0);
            acc[1][1] = __builtin_amdgcn_mfma_f64_16x16x4f64(a1, b1, acc[1][1], 0, 0, 0);
            acc[1][2] = __builtin_amdgcn_mfma_f64_16x16x4f64(a1, b2, acc[1][2], 0, 0, 0);
            acc[1][3] = __builtin_amdgcn_mfma_f64_16x16x4f64(a1, b3, acc[1][3], 0, 0, 0);
        }
        __syncthreads();
    }

    // epilogue: D[i][j]: j = lane&15, i = (lane>>4) + 4n (verified L1)
    #pragma unroll
    for (int ct = 0; ct < 4; ++ct) {
        int col = colb + wn * 64 + ct * 16 + li;
        double bb = (double)bhh[col];
        #pragma unroll
        for (int rt = 0; rt < 2; ++rt) {
            #pragma unroll
            for (int n = 0; n < 4; ++n) {
                int rL = wm * 32 + rt * 16 + kq + 4 * n;
                double e = (double)emb[(size_t)sd[rL] * NH + col];
                double z = acc[rt][ct][n] + bb + e;
                states_out[(size_t)(rowb + rL) * NH + col] = (float)tanh(z);
            }
        }
    }
}

// ---------------- finalize: d_out = [hist as float (524288), scores as float (32768)]
__global__ void k_final(const unsigned char* __restrict__ hist,
                        const double* __restrict__ scores,
                        float* __restrict__ out)
{
    int i = blockIdx.x * 256 + threadIdx.x;
    const int nh = BKROWS * NDEPTH;      // 524288
    if (i < nh) out[i] = (float)hist[i];
    else if (i < nh + BKROWS) out[i] = (float)scores[i - nh];
}

extern "C" void kernel_launch(void* const* d_in, const int* in_sizes, int n_in,
                              void* d_out, int out_size, void* d_ws, size_t ws_size,
                              hipStream_t stream) {
    // inputs: env(unused), root_state, W_logits, b_logits, W_hh, b_hh, emb, beams(=128)
    const float* root = (const float*)d_in[1];
    const float* Wl   = (const float*)d_in[2];
    const float* bl   = (const float*)d_in[3];
    const float* Whh  = (const float*)d_in[4];
    const float* bhh  = (const float*)d_in[5];
    const float* emb  = (const float*)d_in[6];

    char* ws = (char*)d_ws;
    double* scores       = (double*)(ws + 0);             //    262,144
    float*  sA           = (float*)(ws + 262144);         // 67,108,864
    float*  sB           = (float*)(ws + 67371008);       // 67,108,864
    int*    parent       = (int*)(ws + 134479872);        //    131,072
    int*    decs         = (int*)(ws + 134610944);        //    131,072
    unsigned char* hA    = (unsigned char*)(ws + 134742016); // 524,288
    unsigned char* hB    = (unsigned char*)(ws + 135266304); // 524,288
    // total 135,790,592 bytes (<= proven 155,713,536)

    k_init<<<65536, 256, 0, stream>>>(root, sA, scores, hA);

    float* scur = sA; float* snxt = sB;
    unsigned char* hcur = hA; unsigned char* hnxt = hB;
    for (int t = 0; t < NDEPTH; ++t) {
        k_ltk<<<256, 512, 67584, stream>>>(scur, Wl, bl, scores, parent, decs, hcur, hnxt, t);
        k_rnn<<<dim3(256, 4), 512, 0, stream>>>(scur, Whh, bhh, emb, parent, decs, snxt);
        { float* tmp = scur; scur = snxt; snxt = tmp; }
        { unsigned char* tmp = hcur; hcur = hnxt; hnxt = tmp; }
    }

    k_final<<<2176, 256, 0, stream>>>(hcur, scores, (float*)d_out);
}